// Round 4
// baseline (141.192 us; speedup 1.0000x reference)
//
#include <hip/hip_runtime.h>
#include <hip/hip_bf16.h>

// Problem constants (fixed by the reference).
#define N_NODES 10000
#define DEG     32
#define CH      16
#define IN_DIM  4
#define BATCH   8
#define E_EDGES (N_NODES * DEG)        // 320000
#define WI_STRIDE (E_EDGES * CH)       // 5,120,000 floats between w[i] planes
#define P_COUNT 625                    // 512*625 == E_EDGES : gather period in n
#define LX_STRIDE 36                   // 32 floats/row + 4 pad (16B-aligned)

// Kernel 1: transpose/pad x[B][N][4] -> xt[N+1][B][4] (node-major, 128 B/node).
__global__ __launch_bounds__(256) void lcg_transpose(const float* __restrict__ x,
                                                     float* __restrict__ xt) {
    int t = blockIdx.x * 256 + threadIdx.x;
    if (t < BATCH * N_NODES) {
        int b = t / N_NODES;
        int node = t - b * N_NODES;
        float4 v = *(const float4*)(x + 4 * t);          // x[b][node][0..3]
        *(float4*)(xt + node * 32 + b * 4) = v;
    } else if (t < BATCH * N_NODES + 8) {
        int r = t - BATCH * N_NODES;                     // zero pad row N_NODES
        *(float4*)(xt + N_NODES * 32 + r * 4) = make_float4(0.f, 0.f, 0.f, 0.f);
    }
}

// Kernel 2: one block per p. Gather index k = (512n+16d+c) mod 320000 and
// n = p+625j share k = 512p + 16d + c -> edges[512p..512p+512).
// Stage A: gather 512 node-rows (128 B, full-line) into LDS.
// Stage B: thread = (cq fast, j, bq): owns c-quad 4cq..4cq+3 and batches
// {2bq, 2bq+1}. Weights load as float4 (16 B/lane, 4 lanes = full 64 B line
// per j) -> ~8 KB outstanding per wave with unroll 2: HBM-saturating MLP.
__global__ __launch_bounds__(256, 2) void lcg_main(
    const float* __restrict__ xt,     // [N+1][32]
    const int*   __restrict__ edges,  // [E]
    const float* __restrict__ w,      // [4][E][16]
    float*       __restrict__ out)    // [8][N][16]
{
    __shared__ float lx[512 * LX_STRIDE];   // 73728 B -> 2 blocks/CU

    int p = blockIdx.x;
    int t = threadIdx.x;

    // ---- Stage A: edges + gather into LDS ----
    {
        int sub = t & 7;              // which float4 of the 128 B node row
        int rg  = t >> 3;             // 0..31 ; rows s = rg + 32k
        const int* ep = edges + 512 * p;
        int nd[16];
#pragma unroll
        for (int k = 0; k < 16; k++) nd[k] = ep[rg + 32 * k];
#pragma unroll
        for (int k = 0; k < 16; k++) {
            int s = rg + 32 * k;
            float4 v = *(const float4*)(xt + nd[k] * 32 + sub * 4);
            *(float4*)(&lx[s * LX_STRIDE + sub * 4]) = v;
        }
    }
    __syncthreads();

    // ---- Stage B ----
    int cq = t & 3;                   // c-quad (lanes fast -> 64 B line per j)
    int j  = (t >> 2) & 15;           // node group: n = p + 625 j
    int bq = t >> 6;                  // batch pair (wave-uniform)
    int n  = p + P_COUNT * j;

    const float* wb = w + n * (DEG * CH) + 4 * cq;  // w[0][32n][4cq]
    float accA[4] = {0.f, 0.f, 0.f, 0.f};          // batch 2bq,   channels cc
    float accB[4] = {0.f, 0.f, 0.f, 0.f};          // batch 2bq+1

#pragma unroll 2
    for (int d = 0; d < DEG; d++) {
        float4 w0 = *(const float4*)(wb + d * CH);
        float4 w1 = *(const float4*)(wb + d * CH + WI_STRIDE);
        float4 w2 = *(const float4*)(wb + d * CH + 2 * WI_STRIDE);
        float4 w3 = *(const float4*)(wb + d * CH + 3 * WI_STRIDE);
        const float* lrow = &lx[(16 * d + 4 * cq) * LX_STRIDE + 8 * bq];

#define CC_STEP(cc, s0, s1, s2, s3)                                         \
        {                                                                   \
            float4 xa = *(const float4*)(lrow + (cc) * LX_STRIDE);          \
            float4 xb = *(const float4*)(lrow + (cc) * LX_STRIDE + 4);      \
            accA[cc] += xa.x * (s0) + xa.y * (s1) + xa.z * (s2) + xa.w * (s3); \
            accB[cc] += xb.x * (s0) + xb.y * (s1) + xb.z * (s2) + xb.w * (s3); \
        }
        CC_STEP(0, w0.x, w1.x, w2.x, w3.x)
        CC_STEP(1, w0.y, w1.y, w2.y, w3.y)
        CC_STEP(2, w0.z, w1.z, w2.z, w3.z)
        CC_STEP(3, w0.w, w1.w, w2.w, w3.w)
#undef CC_STEP
    }

    int ob = n * CH + 4 * cq;
    *(float4*)(out + (2 * bq + 0) * (N_NODES * CH) + ob) =
        make_float4(accA[0], accA[1], accA[2], accA[3]);
    *(float4*)(out + (2 * bq + 1) * (N_NODES * CH) + ob) =
        make_float4(accB[0], accB[1], accB[2], accB[3]);
}

extern "C" void kernel_launch(void* const* d_in, const int* in_sizes, int n_in,
                              void* d_out, int out_size, void* d_ws, size_t ws_size,
                              hipStream_t stream) {
    const float* x     = (const float*)d_in[0];   // [8][10000][4] f32
    const int*   edges = (const int*)d_in[1];     // [320000] int
    const float* w     = (const float*)d_in[2];   // [4][320000][16] f32
    float* out = (float*)d_out;                   // [8][10000][16] f32
    float* xt  = (float*)d_ws;                    // (10001*32) f32 = 1.28 MB

    int tr_total  = BATCH * N_NODES + 8;                  // 80008
    int tr_blocks = (tr_total + 255) / 256;               // 313
    lcg_transpose<<<tr_blocks, 256, 0, stream>>>(x, xt);

    lcg_main<<<P_COUNT, 256, 0, stream>>>(xt, edges, w, out);
}